// Round 7
// baseline (1109.693 us; speedup 1.0000x reference)
//
#include <hip/hip_runtime.h>
#include <hip/hip_bf16.h>

#define H 2048
#define FDIM 1408
#define NE 64
#define CAP 512
#define NTOK 2048
#define FSH 2816

typedef float  f32x4  __attribute__((ext_vector_type(4)));
typedef float  f32x2  __attribute__((ext_vector_type(2)));
typedef short  s16x8  __attribute__((ext_vector_type(8)));
typedef unsigned short u16;
typedef u16    u16x4v __attribute__((ext_vector_type(4)));

__device__ __forceinline__ u16 f2bf(float f) {
    union { float f; unsigned u; } v; v.f = f;
    unsigned u = v.u;
    u += 0x7fffu + ((u >> 16) & 1u);
    return (u16)(u >> 16);
}
__device__ __forceinline__ float bf2f(u16 b) {
    union { unsigned u; float f; } v; v.u = ((unsigned)b) << 16;
    return v.f;
}
__device__ __forceinline__ void glds16(const u16* g, u16* l) {
    __builtin_amdgcn_global_load_lds(
        (const __attribute__((address_space(1))) unsigned int*)g,
        (__attribute__((address_space(3))) unsigned int*)l, 16, 0, 0);
}

#define BAR() do { asm volatile("s_waitcnt lgkmcnt(0)" ::: "memory"); \
                   __builtin_amdgcn_s_barrier(); } while (0)
#define WAIT_VM(N)  asm volatile("s_waitcnt vmcnt(" #N ")" ::: "memory")
#define SCHED_FENCE() __builtin_amdgcn_sched_barrier(0)

// ---------------- x fp32 -> bf16 once ----------------
__global__ __launch_bounds__(256) void xcvt(const float* __restrict__ x, u16* __restrict__ xb) {
    int i = blockIdx.x * 256 + threadIdx.x;
    const float4 a = ((const float4*)x)[2 * i];
    const float4 b = ((const float4*)x)[2 * i + 1];
    u16 v[8] = { f2bf(a.x), f2bf(a.y), f2bf(a.z), f2bf(a.w),
                 f2bf(b.x), f2bf(b.y), f2bf(b.z), f2bf(b.w) };
    *(s16x8*)(xb + (size_t)i * 8) = *(s16x8*)v;
}

// ---------------- init ----------------
__global__ void init_cnt(int* __restrict__ c) { c[threadIdx.x] = 0; }

// ---------------- gate: logits -> softmax -> top6 -> slot assign ----------------
__global__ __launch_bounds__(64) void gate_topk(
    const float* __restrict__ xg, const float* __restrict__ gw,
    int* __restrict__ cnt, int* __restrict__ tok_of,
    int* __restrict__ slot_enc, float* __restrict__ tw)
{
    const int t = blockIdx.x;
    const int lane = threadIdx.x;
    __shared__ float4 xs[512];
    const float4* xr = (const float4*)(xg + (size_t)t * H);
    #pragma unroll
    for (int i = 0; i < 8; ++i) xs[i * 64 + lane] = xr[i * 64 + lane];
    __syncthreads();

    const float4* gr = (const float4*)(gw + (size_t)lane * H);
    float acc = 0.f;
    #pragma unroll 4
    for (int i = 0; i < 512; ++i) {
        float4 a = xs[i], b = gr[i];
        acc += a.x * b.x + a.y * b.y + a.z * b.z + a.w * b.w;
    }
    float m = acc;
    #pragma unroll
    for (int off = 32; off; off >>= 1) m = fmaxf(m, __shfl_xor(m, off));
    float p = __expf(acc - m);
    float s = p;
    #pragma unroll
    for (int off = 32; off; off >>= 1) s += __shfl_xor(s, off);
    p = p / s;

    float myw = 0.f; int mye = 0;
    float v = p;
    for (int k = 0; k < 6; ++k) {
        float bv = v; int bi = lane;
        #pragma unroll
        for (int off = 32; off; off >>= 1) {
            float ov = __shfl_xor(bv, off);
            int   oi = __shfl_xor(bi, off);
            if (ov > bv || (ov == bv && oi < bi)) { bv = ov; bi = oi; }
        }
        if (lane == k)  { myw = bv; mye = bi; }
        if (lane == bi) v = -1.f;
    }
    if (lane < 6) {
        int slot = atomicAdd(&cnt[mye], 1);
        int enc = -1;
        if (slot < CAP) { tok_of[mye * CAP + slot] = t; enc = mye * CAP + slot; }
        slot_enc[t * 6 + lane] = enc;
        tw[t * 6 + lane] = myw;               // SCALE == 1.0
    }
}

// ---------------- fused gate+up grouped GEMM + SiLU ----------------
// BM=256, BN=32/mat, BK=32. A: glds double-buf [256][32] w/ 2-bit source swizzle.
// B: k8-blocked [mat][4][32][8], single reg set depth-2, single LDS buf.
// Two lgkm-only barriers/iter; counted vmcnt keeps next B in flight. 36KB LDS.
template<bool ROUTED>
__global__ __launch_bounds__(256, 3) void dual_gemm(
    const u16* __restrict__ xbf, const int* __restrict__ tok_of,
    const int* __restrict__ cnt_arr, const float* __restrict__ wg,
    const float* __restrict__ wu, u16* __restrict__ act, int Fd)
{
    __shared__ u16 As[2][256 * 32];       // 32 KB
    __shared__ u16 Bgs[4 * 32 * 8];       // 2 KB (single buf)
    __shared__ u16 Bus[4 * 32 * 8];       // 2 KB

    int e = 0, cnt, m0, f0;
    if constexpr (ROUTED) {
        e = blockIdx.z;
        cnt = cnt_arr[e]; cnt = cnt < CAP ? cnt : CAP;
        f0 = blockIdx.x * 32; m0 = blockIdx.y * 256;
        if (m0 >= cnt) return;
    } else {
        cnt = NTOK;
        m0 = blockIdx.x * 256; f0 = blockIdx.y * 32;
    }

    const float* wg_e = wg;
    const float* wu_e = wu;
    u16* act_e = act;
    if constexpr (ROUTED) {
        wg_e += (size_t)e * H * Fd;
        wu_e += (size_t)e * H * Fd;
        act_e += (size_t)e * CAP * Fd;
    }

    const int tid = threadIdx.x;
    const int lane = tid & 63;
    const int wv = tid >> 6;
    const int NT = H / 32;                // 64

    // ---- A glds: 4 chunks/thread; chunk q covers rows (q*4+wv)*16 .. +15 ----
    // lane l -> row +(l>>2); source granule g = (l&3)^((l>>3)&3) (pre-swizzle)
    const int gA = ((lane & 3) ^ ((lane >> 3) & 3)) * 8;
    const u16* agp[4];
    #pragma unroll
    for (int q = 0; q < 4; ++q) {
        int rloc = (q * 4 + wv) * 16 + (lane >> 2);
        int srow = m0 + rloc;
        const u16* base;
        if constexpr (ROUTED) {
            const int* tok = tok_of + e * CAP;
            base = xbf + (size_t)tok[srow < cnt ? srow : 0] * H;
        } else {
            base = xbf + (size_t)srow * H;
        }
        agp[q] = base + gA;
    }
    // ---- B geometry ----
    const int mat = tid >> 7;
    const int bb = tid & 127;
    const float* bsrc;
    int n2 = 0, kq = 0, dr = 0, dcq = 0;
    if constexpr (ROUTED) {
        n2 = bb & 15; kq = bb >> 4;                // 16x2=32 cols, 8x4=32 k
        bsrc = (mat ? wu_e : wg_e) + (size_t)(kq * 4) * Fd + f0 + n2 * 2;
    } else {
        dr = bb >> 2; dcq = bb & 3;                // 32 cols, 4x8=32 k
        bsrc = (mat ? wu_e : wg_e) + (size_t)(f0 + dr) * H + dcq * 8;
    }

    f32x4 accg[4][2], accu[4][2];
    const f32x4 zero4 = {0.f, 0.f, 0.f, 0.f};
    #pragma unroll
    for (int i = 0; i < 4; ++i)
        #pragma unroll
        for (int j = 0; j < 2; ++j) { accg[i][j] = zero4; accu[i][j] = zero4; }

    f32x2 bR2[4];
    f32x4 bR4[2];

    auto GLDS_A = [&](int kt, int b) {
        #pragma unroll
        for (int q = 0; q < 4; ++q)
            glds16(agp[q] + kt * 32, &As[b][(q * 4 + wv) * 512]);
    };
    auto LOADB = [&](int kt) {
        if constexpr (ROUTED) {
            #pragma unroll
            for (int j = 0; j < 4; ++j)
                bR2[j] = *(const f32x2*)(bsrc + ((size_t)kt * 32 + j) * Fd);
        } else {
            bR4[0] = *(const f32x4*)(bsrc + kt * 32);
            bR4[1] = *(const f32x4*)(bsrc + kt * 32 + 4);
        }
    };
    auto STOREB = [&]() {
        u16* Bdst = mat ? Bus : Bgs;
        if constexpr (ROUTED) {
            #pragma unroll
            for (int c = 0; c < 2; ++c) {
                u16x4v v; v[0] = f2bf(bR2[0][c]); v[1] = f2bf(bR2[1][c]);
                          v[2] = f2bf(bR2[2][c]); v[3] = f2bf(bR2[3][c]);
                *(u16x4v*)&Bdst[(kq >> 1) * 256 + (n2 * 2 + c) * 8 + (kq & 1) * 4] = v;
            }
        } else {
            u16 v[8];
            v[0]=f2bf(bR4[0][0]); v[1]=f2bf(bR4[0][1]); v[2]=f2bf(bR4[0][2]); v[3]=f2bf(bR4[0][3]);
            v[4]=f2bf(bR4[1][0]); v[5]=f2bf(bR4[1][1]); v[6]=f2bf(bR4[1][2]); v[7]=f2bf(bR4[1][3]);
            *(s16x8*)&Bdst[dcq * 256 + dr * 8] = *(s16x8*)v;
        }
    };
    auto COMPUTE = [&](int b) {
        __builtin_amdgcn_s_setprio(1);
        const int j8 = lane >> 4;                       // k8 group
        const int p8 = (j8 ^ ((lane >> 1) & 3)) * 8;    // A swizzled granule
        s16x8 a[4], bg[2], bu[2];
        #pragma unroll
        for (int mi = 0; mi < 4; ++mi) {
            int r = wv * 64 + mi * 16 + (lane & 15);
            a[mi] = *(const s16x8*)&As[b][r * 32 + p8];
        }
        #pragma unroll
        for (int ni = 0; ni < 2; ++ni) {
            int c = ni * 16 + (lane & 15);
            bg[ni] = *(const s16x8*)&Bgs[j8 * 256 + c * 8];
            bu[ni] = *(const s16x8*)&Bus[j8 * 256 + c * 8];
        }
        #pragma unroll
        for (int mi = 0; mi < 4; ++mi)
            #pragma unroll
            for (int ni = 0; ni < 2; ++ni) {
                accg[mi][ni] = __builtin_amdgcn_mfma_f32_16x16x32_bf16(a[mi], bg[ni], accg[mi][ni], 0, 0, 0);
                accu[mi][ni] = __builtin_amdgcn_mfma_f32_16x16x32_bf16(a[mi], bu[ni], accu[mi][ni], 0, 0, 0);
            }
        __builtin_amdgcn_s_setprio(0);
    };

    // ---- prologue ----
    GLDS_A(0, 0); SCHED_FENCE();
    LOADB(0);     SCHED_FENCE();
    STOREB();                       // auto-drains B(0) (and A(0), prologue-only)
    LOADB(1);     SCHED_FENCE();
    BAR(); SCHED_FENCE();

    // invariant: As[kt&1]=A(kt); Bgs/Bus=B(kt); regs=B(kt+1) in flight/done
    for (int kt = 0; kt < NT; ++kt) {
        const int b = kt & 1;
        if (kt + 1 < NT) GLDS_A(kt + 1, b ^ 1);
        SCHED_FENCE();
        COMPUTE(b);
        BAR();                      // BAR1: all waves done reading Bs
        if (kt + 1 < NT) {
            STOREB();               // auto vmcnt keeps A(kt+1) in flight
            if (kt + 2 < NT) LOADB(kt + 2);
        }
        SCHED_FENCE();
        if (kt + 1 < NT) {
            if (kt + 2 < NT) {
                if constexpr (ROUTED) { WAIT_VM(4); } else { WAIT_VM(2); }
            } else { WAIT_VM(0); }
        }
        BAR(); SCHED_FENCE();       // BAR2: publish As[b^1], Bs
    }

    // ---- epilogue: silu(g)*u -> bf16 act (linear layout) ----
    #pragma unroll
    for (int mi = 0; mi < 4; ++mi)
        #pragma unroll
        for (int ni = 0; ni < 2; ++ni)
            #pragma unroll
            for (int r = 0; r < 4; ++r) {
                int srow = m0 + wv * 64 + mi * 16 + (lane >> 4) * 4 + r;
                if (srow < cnt) {
                    int fc = f0 + ni * 16 + (lane & 15);
                    float g = accg[mi][ni][r], u = accu[mi][ni][r];
                    float aa = (g / (1.f + __expf(-g))) * u;
                    act_e[(size_t)srow * Fd + fc] = f2bf(aa);
                }
            }
}

// ---------------- down-proj grouped GEMM ----------------
// BM=256, BN=64, BK=32. Same pipeline/layout family as dual_gemm.
template<bool ROUTED>
__global__ __launch_bounds__(256, 3) void down_gemm(
    const u16* __restrict__ actA, const float* __restrict__ wdn,
    void* __restrict__ outp, const int* __restrict__ cnt_arr, int Kd)
{
    __shared__ u16 As[2][256 * 32];       // 32 KB
    __shared__ u16 Bs[4 * 64 * 8];        // 4 KB (single buf)

    int e = 0, cnt, m0, n0;
    if constexpr (ROUTED) {
        e = blockIdx.z;
        cnt = cnt_arr[e]; cnt = cnt < CAP ? cnt : CAP;
        n0 = blockIdx.x * 64; m0 = blockIdx.y * 256;
        if (m0 >= cnt) return;
    } else {
        cnt = NTOK;
        m0 = blockIdx.x * 256; n0 = blockIdx.y * 64;
    }

    const u16* A_e = actA;
    const float* B_e = wdn;
    if constexpr (ROUTED) {
        A_e += (size_t)e * CAP * Kd;
        B_e += (size_t)e * Kd * H;
    }
    const int NT = Kd / 32;               // 44 or 88
    const int tid = threadIdx.x, lane = tid & 63, wv = tid >> 6;

    const int gA = ((lane & 3) ^ ((lane >> 3) & 3)) * 8;
    const u16* agp[4];
    #pragma unroll
    for (int q = 0; q < 4; ++q) {
        int rloc = (q * 4 + wv) * 16 + (lane >> 2);
        agp[q] = A_e + (size_t)(m0 + rloc) * Kd + gA;
    }
    const float* bsrc;
    int n2 = 0, kq = 0, dr = 0, dcq = 0;
    if constexpr (ROUTED) {
        n2 = tid & 31; kq = tid >> 5;              // 32x2=64 cols, 8x4=32 k
        bsrc = B_e + (size_t)(kq * 4) * H + n0 + n2 * 2;
    } else {
        dr = tid >> 2; dcq = tid & 3;              // 64 cols, 4x8=32 k
        bsrc = B_e + (size_t)(n0 + dr) * FSH + dcq * 8;
    }

    f32x4 acc[4][4];
    const f32x4 zero4 = {0.f, 0.f, 0.f, 0.f};
    #pragma unroll
    for (int i = 0; i < 4; ++i)
        #pragma unroll
        for (int j = 0; j < 4; ++j) acc[i][j] = zero4;

    f32x2 bR2[4];
    f32x4 bR4[2];

    auto GLDS_A = [&](int kt, int b) {
        #pragma unroll
        for (int q = 0; q < 4; ++q)
            glds16(agp[q] + kt * 32, &As[b][(q * 4 + wv) * 512]);
    };
    auto LOADB = [&](int kt) {
        if constexpr (ROUTED) {
            #pragma unroll
            for (int j = 0; j < 4; ++j)
                bR2[j] = *(const f32x2*)(bsrc + ((size_t)kt * 32 + j) * H);
        } else {
            bR4[0] = *(const f32x4*)(bsrc + kt * 32);
            bR4[1] = *(const f32x4*)(bsrc + kt * 32 + 4);
        }
    };
    auto STOREB = [&]() {
        if constexpr (ROUTED) {
            #pragma unroll
            for (int c = 0; c < 2; ++c) {
                u16x4v v; v[0] = f2bf(bR2[0][c]); v[1] = f2bf(bR2[1][c]);
                          v[2] = f2bf(bR2[2][c]); v[3] = f2bf(bR2[3][c]);
                *(u16x4v*)&Bs[(kq >> 1) * 512 + (n2 * 2 + c) * 8 + (kq & 1) * 4] = v;
            }
        } else {
            u16 v[8];
            v[0]=f2bf(bR4[0][0]); v[1]=f2bf(bR4[0][1]); v[2]=f2bf(bR4[0][2]); v[3]=f2bf(bR4[0][3]);
            v[4]=f2bf(bR4[1][0]); v[5]=f2bf(bR4[1][1]); v[6]=f2bf(bR4[1][2]); v[7]=f2bf(bR4[1][3]);
            *(s16x8*)&Bs[dcq * 512 + dr * 8] = *(s16x8*)v;
        }
    };
    auto COMPUTE = [&](int b) {
        __builtin_amdgcn_s_setprio(1);
        const int j8 = lane >> 4;
        const int p8 = (j8 ^ ((lane >> 1) & 3)) * 8;
        s16x8 a[4], bf[4];
        #pragma unroll
        for (int mi = 0; mi < 4; ++mi) {
            int r = wv * 64 + mi * 16 + (lane & 15);
            a[mi] = *(const s16x8*)&As[b][r * 32 + p8];
        }
        #pragma unroll
        for (int ni = 0; ni < 4; ++ni) {
            int c = ni * 16 + (lane & 15);
            bf[ni] = *(const s16x8*)&Bs[j8 * 512 + c * 8];
        }
        #pragma unroll
        for (int mi = 0; mi < 4; ++mi)
            #pragma unroll
            for (int ni = 0; ni < 4; ++ni)
                acc[mi][ni] = __builtin_amdgcn_mfma_f32_16x16x32_bf16(a[mi], bf[ni], acc[mi][ni], 0, 0, 0);
        __builtin_amdgcn_s_setprio(0);
    };

    GLDS_A(0, 0); SCHED_FENCE();
    LOADB(0);     SCHED_FENCE();
    STOREB();
    LOADB(1);     SCHED_FENCE();
    BAR(); SCHED_FENCE();

    for (int kt = 0; kt < NT; ++kt) {
        const int b = kt & 1;
        if (kt + 1 < NT) GLDS_A(kt + 1, b ^ 1);
        SCHED_FENCE();
        COMPUTE(b);
        BAR();
        if (kt + 1 < NT) {
            STOREB();
            if (kt + 2 < NT) LOADB(kt + 2);
        }
        SCHED_FENCE();
        if (kt + 1 < NT) {
            if (kt + 2 < NT) {
                if constexpr (ROUTED) { WAIT_VM(4); } else { WAIT_VM(2); }
            } else { WAIT_VM(0); }
        }
        BAR(); SCHED_FENCE();
    }

    #pragma unroll
    for (int mi = 0; mi < 4; ++mi)
        #pragma unroll
        for (int ni = 0; ni < 4; ++ni)
            #pragma unroll
            for (int r = 0; r < 4; ++r) {
                int srow = m0 + wv * 64 + mi * 16 + (lane >> 4) * 4 + r;
                if (srow < cnt) {
                    int col = n0 + ni * 16 + (lane & 15);
                    float vv = acc[mi][ni][r];
                    if constexpr (ROUTED)
                        ((u16*)outp)[(size_t)e * CAP * H + (size_t)srow * H + col] = f2bf(vv);
                    else
                        ((float*)outp)[(size_t)srow * H + col] = vv;
                }
            }
}

// ---------------- combine: y += sum_k w_k * d[enc_k] ----------------
__global__ __launch_bounds__(256) void combine(
    float* __restrict__ y, const u16* __restrict__ d,
    const int* __restrict__ slot_enc, const float* __restrict__ tw)
{
    const int t = blockIdx.x, tid = threadIdx.x;
    int enc[6]; float w[6];
    #pragma unroll
    for (int k = 0; k < 6; ++k) {
        enc[k] = slot_enc[t * 6 + k];
        w[k] = tw[t * 6 + k];
    }
    float4* yrow = (float4*)(y + (size_t)t * H);
    #pragma unroll
    for (int it = 0; it < 2; ++it) {
        int h4 = it * 256 + tid;
        float4 acc = yrow[h4];
        #pragma unroll
        for (int k = 0; k < 6; ++k) {
            if (enc[k] >= 0) {
                ushort4 dv = ((const ushort4*)(d + (size_t)enc[k] * H))[h4];
                acc.x += w[k] * bf2f(dv.x);
                acc.y += w[k] * bf2f(dv.y);
                acc.z += w[k] * bf2f(dv.z);
                acc.w += w[k] * bf2f(dv.w);
            }
        }
        yrow[h4] = acc;
    }
}

extern "C" void kernel_launch(void* const* d_in, const int* in_sizes, int n_in,
                              void* d_out, int out_size, void* d_ws, size_t ws_size,
                              hipStream_t stream) {
    const float* x       = (const float*)d_in[0];
    const float* gw      = (const float*)d_in[1];
    const float* w_gate  = (const float*)d_in[2];
    const float* w_up    = (const float*)d_in[3];
    const float* w_down  = (const float*)d_in[4];
    const float* sh_gate = (const float*)d_in[5];
    const float* sh_up   = (const float*)d_in[6];
    const float* sh_down = (const float*)d_in[7];
    float* y = (float*)d_out;

    char* wsb = (char*)d_ws;
    int*   cnt      = (int*)(wsb + 0);                       // 64 ints
    int*   tok_of   = (int*)(wsb + 512);                     // 64*512 ints
    int*   slot_enc = (int*)(wsb + 512 + 131072);            // 2048*6 ints
    float* tw       = (float*)(wsb + 512 + 131072 + 49152);  // 2048*6 floats
    u16*   act      = (u16*)(wsb + 230144);                  // 64*512*1408 bf16
    u16*   actsh    = (u16*)(wsb + 230144 + 92274688);       // 2048*2816 bf16
    u16*   dbuf     = (u16*)(wsb + 230144 + 92274688 + 11534336); // 64*512*2048 bf16
    u16*   xbf      = dbuf;  // alias: xbf (8MB) dead before down_gemm writes dbuf

    init_cnt<<<1, 64, 0, stream>>>(cnt);
    xcvt<<<NTOK * H / 8 / 256, 256, 0, stream>>>(x, xbf);
    gate_topk<<<NTOK, 64, 0, stream>>>(x, gw, cnt, tok_of, slot_enc, tw);
    dual_gemm<true><<<dim3(FDIM / 32, 2, NE), 256, 0, stream>>>(
        xbf, tok_of, cnt, w_gate, w_up, act, FDIM);
    dual_gemm<false><<<dim3(NTOK / 256, FSH / 32, 1), 256, 0, stream>>>(
        xbf, nullptr, nullptr, sh_gate, sh_up, actsh, FSH);
    down_gemm<true><<<dim3(H / 64, 2, NE), 256, 0, stream>>>(
        act, w_down, (void*)dbuf, cnt, FDIM);
    down_gemm<false><<<dim3(NTOK / 256, H / 64, 1), 256, 0, stream>>>(
        actsh, sh_down, (void*)y, nullptr, FSH);
    combine<<<NTOK, 256, 0, stream>>>(y, dbuf, slot_enc, tw);
}